// Round 1
// baseline (101.167 us; speedup 1.0000x reference)
//
#include <hip/hip_runtime.h>

// Problem constants (from reference setup_inputs)
constexpr int NPTS = 8192;   // points per batch
constexpr int NQ   = 2048;   // query points per batch
constexpr int NC   = 64;     // feature channels
constexpr int NS   = 32;     // nsample
constexpr int NCH  = 3 + 1 + NC;           // 68 output channels
constexpr int CS   = NQ * NS;              // channel stride in output (floats)
constexpr int QPB  = 8;      // queries per scan block (8 waves, 512 thr)

// Workspace layout (floats):  ftr : B*NPTS*NC  |  idx : B*NQ*NS (int32)

// R12: barrier-free scan. R11's LDS tiling staged xyz (L2-resident: 96 KB/
// batch) behind 2 barriers/tile with all-8-wave done-voting; one straggler
// wave (edge/corner query, scan depth 1900-3900 pts) dragged 7 finished
// waves through extra stagings + vmcnt(0) drains. Mean scan depth is only
// ~650 pts (heavy cube clipping) -> the scan is ~2-3 us of VALU; everything
// else was structure. Now: wave-per-query, direct L2 reads (64 float3 =
// 768 B contiguous per wave), 1-deep prefetch, per-wave early exit, zero
// barriers in the scan path. LDS = idx rows only (union w/ transpose tile).

union KLds {
    int   idx[QPB][NS];      // 1 KB   (scan path)
    float tile[NC][65];      // 16.6 KB (transpose path)
};

__device__ __forceinline__ unsigned prefix_popc(unsigned long long m) {
    return __builtin_amdgcn_mbcnt_hi((unsigned)(m >> 32),
           __builtin_amdgcn_mbcnt_lo((unsigned)m, 0u));
}

__global__ __launch_bounds__(512, 8) void scan_trans_kernel(
    const float* __restrict__ xyz,    // (B, NPTS, 3)
    const float* __restrict__ nxyz,   // (B, NQ, 3)
    const float* __restrict__ feat,   // (B, NC, NPTS)
    float* __restrict__ ftr,          // (B, NPTS, NC)
    int* __restrict__ gidx,           // (B, NQ, NS)
    float* __restrict__ out,          // (B, NCH, NQ, NS)
    int ntrans)
{
    __shared__ KLds u;
    const int bx = blockIdx.x;
    const int t  = threadIdx.x;

    if (bx < ntrans) {
        // ---- feature transpose: one 64-pt x 64-ch tile, 512 thr ----
        const int b  = bx >> 7;               // 128 t-blocks per batch
        const int tl = bx & 127;
        const int n0 = tl * 64;
        const float* fb = feat + (size_t)b * NC * NPTS;
        const int pl = t & 63;
        const int c0 = t >> 6;                // 0..7
        #pragma unroll
        for (int i = 0; i < 8; ++i) {         // coalesced 256B rows
            const int c = c0 + 8 * i;
            u.tile[c][pl] = fb[(size_t)c * NPTS + n0 + pl];
        }
        __syncthreads();
        float* tb = ftr + ((size_t)b * NPTS + n0) * NC;
        #pragma unroll
        for (int i = 0; i < 8; ++i) {         // coalesced 256B per point
            const int pp = c0 + 8 * i;
            tb[(size_t)pp * NC + pl] = u.tile[pl][pp];   // (pl*65+pp)%32: free
        }
        return;
    }

    // ---- scan: 1 wave = 1 query, barrier-free, direct-from-L2 ----
    const int sb   = bx - ntrans;
    const int qpb  = NQ / QPB;                // 256 scan-blocks per batch
    const int b    = sb / qpb;
    const int p0   = (sb - b * qpb) * QPB;
    const int lane = t & 63;
    const int wave = t >> 6;                  // 0..7
    const int p    = p0 + wave;
    const float* xb = xyz + (size_t)b * NPTS * 3;
    const float3* xb3 = reinterpret_cast<const float3*>(xb);
    int* idx_row = u.idx[wave];

    const float qx = nxyz[((size_t)b * NQ + p) * 3 + 0];
    const float qy = nxyz[((size_t)b * NQ + p) * 3 + 1];
    const float qz = nxyz[((size_t)b * NQ + p) * 3 + 2];

    int cnt = 0;      // wave-uniform hit count
    int first = -1;   // wave-uniform first-hit index

    // 128 pts/iter (2 float3/lane = 768B x2 contiguous per wave, L2-hit),
    // next chunk prefetched before processing current -> load latency hides
    // under the ballot/VALU phase. Strict per-op rounding in the reference's
    // evaluation order: q<1.0 is discontinuous -> no FMA contraction allowed.
    float3 A0 = xb3[lane];
    float3 A1 = xb3[lane + 64];
    for (int base = 0;;) {
        const int nb = base + 128;
        const int pf = nb & (NPTS - 1);       // clamped prefetch base (in-bounds)
        const float3 B0 = xb3[pf + lane];
        const float3 B1 = xb3[pf + lane + 64];

        const float dxA = __fsub_rn(qx, A0.x);
        const float dyA = __fsub_rn(qy, A0.y);
        const float dzA = __fsub_rn(qz, A0.z);
        const float qA  = __fadd_rn(__fadd_rn(
                            __fmul_rn(__fmul_rn(dxA, dxA), 25.0f),
                            __fmul_rn(__fmul_rn(dyA, dyA), 6.25f)),
                            __fmul_rn(__fmul_rn(dzA, dzA), 25.0f));
        const float dxB = __fsub_rn(qx, A1.x);
        const float dyB = __fsub_rn(qy, A1.y);
        const float dzB = __fsub_rn(qz, A1.z);
        const float qB  = __fadd_rn(__fadd_rn(
                            __fmul_rn(__fmul_rn(dxB, dxB), 25.0f),
                            __fmul_rn(__fmul_rn(dyB, dyB), 6.25f)),
                            __fmul_rn(__fmul_rn(dzB, dzB), 25.0f));
        const bool hitA = qA < 1.0f;
        const bool hitB = qB < 1.0f;

        const unsigned long long m0 = __ballot(hitA);
        const unsigned long long m1 = __ballot(hitB);
        if (first < 0) {                      // wave-uniform
            if (m0 != 0ull)      first = base + __builtin_ctzll(m0);
            else if (m1 != 0ull) first = base + 64 + __builtin_ctzll(m1);
        }
        if (hitA) {
            const int pos = cnt + (int)prefix_popc(m0);
            if (pos < NS) idx_row[pos] = base + lane;
        }
        const int c0h = __popcll(m0);
        if (hitB) {
            const int pos = cnt + c0h + (int)prefix_popc(m1);
            if (pos < NS) idx_row[pos] = base + 64 + lane;
        }
        cnt += c0h + __popcll(m1);

        base = nb;
        if (cnt >= NS || base >= NPTS) break; // wave-uniform early exit
        A0 = B0;
        A1 = B1;
    }

    if (cnt < NS) {                           // <32 hits in whole cloud
        const int f = (cnt == 0) ? 0 : first; // pad (0 if empty)
        if (lane < NS && lane >= cnt) idx_row[lane] = f;
    }

    // epilogue: lanes 0..31 emit idx + channels 0..3
    if (lane < NS) {
        const int s = lane;
        const int j = idx_row[s];             // same-wave LDS RAW: safe
        gidx[((size_t)b * NQ + p) * NS + s] = j;

        const float px = xb[3 * j + 0];
        const float py = xb[3 * j + 1];
        const float pz = xb[3 * j + 2];
        const float dx = __fsub_rn(px, qx);
        const float dy = __fsub_rn(py, qy);
        const float dz = __fsub_rn(pz, qz);
        const float d2 = __fadd_rn(__fadd_rn(__fmul_rn(dx, dx), __fmul_rn(dy, dy)),
                                   __fmul_rn(dz, dz));
        const float dist = __fsqrt_rn(d2);
        const float arg  = __fdiv_rn(-__fmul_rn(dist, dist), 0.02f);
        const float density = __fmul_rn(expf(arg), 4.0f);  // /0.25 == *4 exact
        const float gd = __fdiv_rn(1.0f, density);         // inf underflow == ref

        float* ob = out + ((size_t)b * NCH * NQ + p) * NS + s;
        ob[0 * (size_t)CS] = px;
        ob[1 * (size_t)CS] = py;
        ob[2 * (size_t)CS] = pz;
        ob[3 * (size_t)CS] = gd;
    }
}

// ---------------------------------------------------------------------------
// K2: feature grouping (R4 version, measured at write-BW floor ~11-13 us).
// ---------------------------------------------------------------------------
__global__ __launch_bounds__(512, 8) void group_kernel(
    const int* __restrict__ gidx,     // (B, NQ, NS)
    const float* __restrict__ ftr,    // (B, NPTS, NC)
    float* __restrict__ out,          // (B, NCH, NQ, NS)
    int B)
{
    __shared__ float ldsc[NC][33];

    const int g = blockIdx.x;
    int b, p;
    if (B == 4) {
        b = (g & 7) >> 1;                     // XCD-pair -> batch
        p = ((g >> 3) << 1) | (g & 1);
    } else {
        b = g / NQ;
        p = g - b * NQ;
    }
    const int tid = threadIdx.x;

    const int cg = tid & 15;                  // channel group 0..15 (float4)
    const int sl = tid >> 4;                  // sample 0..31
    const int j  = gidx[((size_t)b * NQ + p) * NS + sl];
    const float4 v = ((const float4*)(ftr + ((size_t)b * NPTS + j) * NC))[cg];
    ldsc[4 * cg + 0][sl] = v.x;               // bank (4cg+i+sl)%32 -> 2-way, free
    ldsc[4 * cg + 1][sl] = v.y;
    ldsc[4 * cg + 2][sl] = v.z;
    ldsc[4 * cg + 3][sl] = v.w;
    __syncthreads();

    const int c  = tid >> 3;                  // channel 0..63
    const int s4 = (tid & 7) << 2;            // sample base 0,4,...,28
    float4 w;
    w.x = ldsc[c][s4 + 0];                    // bank (c+s4+i)%32 -> <=2-way, free
    w.y = ldsc[c][s4 + 1];
    w.z = ldsc[c][s4 + 2];
    w.w = ldsc[c][s4 + 3];
    float* op = out + (((size_t)b * NCH + 4 + c) * NQ + p) * NS + s4;
    *(float4*)op = w;                         // 8 x 128B segments per wave store
}

// ---------------------------------------------------------------------------
// Fallback (tiny ws): R1-style fused direct kernel.
// ---------------------------------------------------------------------------
__global__ __launch_bounds__(512, 8) void ellip_direct_kernel(
    const float* __restrict__ xyz,
    const float* __restrict__ nxyz,
    const float* __restrict__ feat,
    float* __restrict__ out)
{
    __shared__ int idx_s[8][NS];

    const int b    = blockIdx.y;
    const int p0   = blockIdx.x * 8;
    const int tid  = threadIdx.x;
    const int lane = tid & 63;
    const int wave = tid >> 6;
    const float* xb = xyz + (size_t)b * NPTS * 3;

    {
        const int p = p0 + wave;
        const float qx = nxyz[((size_t)b * NQ + p) * 3 + 0];
        const float qy = nxyz[((size_t)b * NQ + p) * 3 + 1];
        const float qz = nxyz[((size_t)b * NQ + p) * 3 + 2];
        int cnt = 0, first = -1;
        for (int base = 0; base < NPTS; base += 64) {
            const int i = base + lane;
            const float dx = __fsub_rn(qx, xb[i * 3 + 0]);
            const float dy = __fsub_rn(qy, xb[i * 3 + 1]);
            const float dz = __fsub_rn(qz, xb[i * 3 + 2]);
            const float t0 = __fmul_rn(__fmul_rn(dx, dx), 25.0f);
            const float t1 = __fmul_rn(__fmul_rn(dy, dy), 6.25f);
            const float t2 = __fmul_rn(__fmul_rn(dz, dz), 25.0f);
            const float qv = __fadd_rn(__fadd_rn(t0, t1), t2);
            const bool hit = qv < 1.0f;
            const unsigned long long m = __ballot(hit);
            if (first < 0 && m != 0ull) first = base + __builtin_ctzll(m);
            if (hit) {
                const int pos = cnt + __popcll(m & ((1ull << lane) - 1ull));
                if (pos < NS) idx_s[wave][pos] = i;
            }
            cnt += __popcll(m);
            if (cnt >= NS) break;
        }
        if (cnt < NS) {
            const int f = (cnt == 0) ? 0 : first;
            if (lane < NS && lane >= cnt) idx_s[wave][lane] = f;
        }
    }
    __syncthreads();

    const int s = tid & 31;
    const int h = (tid >> 5) & 1;
    const int q = tid >> 6;
    const int p = p0 + q;
    const int j = idx_s[q][s];
    float* ob = out + ((size_t)b * NCH * NQ + p) * NS + s;

    if (h == 0) {
        const float qx = nxyz[((size_t)b * NQ + p) * 3 + 0];
        const float qy = nxyz[((size_t)b * NQ + p) * 3 + 1];
        const float qz = nxyz[((size_t)b * NQ + p) * 3 + 2];
        const float px = xb[j * 3 + 0], py = xb[j * 3 + 1], pz = xb[j * 3 + 2];
        const float dx = __fsub_rn(px, qx);
        const float dy = __fsub_rn(py, qy);
        const float dz = __fsub_rn(pz, qz);
        const float d2 = __fadd_rn(__fadd_rn(__fmul_rn(dx, dx), __fmul_rn(dy, dy)),
                                   __fmul_rn(dz, dz));
        const float dist = __fsqrt_rn(d2);
        const float arg  = __fdiv_rn(-__fmul_rn(dist, dist), 0.02f);
        const float gd = __fdiv_rn(1.0f, __fmul_rn(expf(arg), 4.0f));
        ob[0 * (size_t)CS] = px;
        ob[1 * (size_t)CS] = py;
        ob[2 * (size_t)CS] = pz;
        ob[3 * (size_t)CS] = gd;
    }
    const float* fb = feat + (size_t)b * NC * NPTS + j;
    #pragma unroll 4
    for (int c = h; c < NC; c += 2)
        ob[(size_t)(4 + c) * CS] = fb[(size_t)c * NPTS];
}

extern "C" void kernel_launch(void* const* d_in, const int* in_sizes, int n_in,
                              void* d_out, int out_size, void* d_ws, size_t ws_size,
                              hipStream_t stream) {
    const float* xyz  = (const float*)d_in[0];   // (B, 8192, 3)
    const float* nxyz = (const float*)d_in[1];   // (B, 2048, 3)
    const float* feat = (const float*)d_in[2];   // (B, 64, 8192)
    float* out = (float*)d_out;                  // (B, 68, 2048, 32)

    const int B = in_sizes[0] / (NPTS * 3);
    const size_t ftr_f = (size_t)B * NPTS * NC;
    const size_t idx_f = (size_t)B * NQ * NS;
    const size_t need  = (ftr_f + idx_f) * 4;

    if (ws_size >= need) {
        float* ftr = (float*)d_ws;
        int*   idx = (int*)(ftr + ftr_f);

        const int ntrans = B * (NPTS / 64);      // 512 transpose blocks (first)
        const int nscan  = B * (NQ / QPB);       // 1024 scan blocks
        scan_trans_kernel<<<dim3(ntrans + nscan), 512, 0, stream>>>(
            xyz, nxyz, feat, ftr, idx, out, ntrans);
        group_kernel<<<dim3(B * NQ), 512, 0, stream>>>(idx, ftr, out, B);
    } else {
        ellip_direct_kernel<<<dim3(NQ / 8, B), 512, 0, stream>>>(xyz, nxyz, feat, out);
    }
}